// Round 1
// baseline (318.276 us; speedup 1.0000x reference)
//
#include <hip/hip_runtime.h>
#include <hip/hip_bf16.h>

typedef float f32x4 __attribute__((ext_vector_type(4)));
typedef short bf16x8 __attribute__((ext_vector_type(8)));

#define B_ 32
#define L_ 1024
#define D_ 64
#define J_ 2047   // 2L-1

__device__ __forceinline__ unsigned short f2bf(float f) {
    union { float f; unsigned u; } x; x.f = f;
    unsigned r = x.u + 0x7FFFu + ((x.u >> 16) & 1u);   // RNE
    return (unsigned short)(r >> 16);
}

__device__ __forceinline__ bf16x8 pack8(const float* p) {
    float4 a = *(const float4*)p;
    float4 b = *(const float4*)(p + 4);
    bf16x8 v;
    v[0] = (short)f2bf(a.x); v[1] = (short)f2bf(a.y);
    v[2] = (short)f2bf(a.z); v[3] = (short)f2bf(a.w);
    v[4] = (short)f2bf(b.x); v[5] = (short)f2bf(b.y);
    v[6] = (short)f2bf(b.z); v[7] = (short)f2bf(b.w);
    return v;
}

// Detect attn_mask storage: 0 = 1-byte bool, 1 = int32 0/1, 2 = float32 0.0/1.0
__global__ void detect_mask_kernel(const unsigned int* __restrict__ mw, int* __restrict__ flag) {
    if (threadIdx.x == 0) {
        int all01 = 1, allf = 1;
        for (int i = 0; i < 64; ++i) {
            unsigned w = mw[i];
            if (w > 1u) all01 = 0;
            if (w != 0u && w != 0x3F800000u) allf = 0;
        }
        *flag = all01 ? 1 : (allf ? 2 : 0);
    }
}

// Kernel 1: logits = (Q K^T + stripe(Qp P^T)) / 8, mask -> -inf, write logits to attn
// area of d_out, track per-row running max & sumexp (online), store stats to ws.
// Block = 256 thr (4 waves), each wave owns 16 rows; grid = B * (L/64).
__global__ __launch_bounds__(256) void k1_logits(
    const float* __restrict__ Q, const float* __restrict__ K,
    const float* __restrict__ QP, const float* __restrict__ P,
    const void* __restrict__ mask, const int* __restrict__ flagp,
    float* __restrict__ attn, float* __restrict__ wmax, float* __restrict__ wsum)
{
    const int flag = *flagp;
    int bid = blockIdx.x;
    bid = (bid & 7) * 64 + (bid >> 3);      // XCD swizzle (512 = 8*64, bijective)
    const int b  = bid >> 4;
    const int rb = bid & 15;
    const int lane = threadIdx.x & 63;
    const int w    = threadIdx.x >> 6;
    const int t0 = rb * 64 + w * 16;
    const int lr = lane & 15;               // A row / B col within fragment
    const int lg = lane >> 4;               // k-group

    bf16x8 aq[2], aqp[2];
    {
        const float* qrow  = Q  + ((b * L_ + t0 + lr) * D_ + lg * 8);
        const float* qprow = QP + ((b * L_ + t0 + lr) * D_ + lg * 8);
        aq[0]  = pack8(qrow);   aq[1]  = pack8(qrow + 32);
        aqp[0] = pack8(qprow);  aqp[1] = pack8(qprow + 32);
    }

    const unsigned char* m8 = (const unsigned char*)mask;
    const int*   m32 = (const int*)mask;
    const float* mf  = (const float*)mask;

    float m_run[4] = {-1e30f, -1e30f, -1e30f, -1e30f};
    float l_run[4] = {0.f, 0.f, 0.f, 0.f};

    for (int c = 0; c < 16; ++c) {
        const int m0 = c * 64;
        // content scores: 4 col-tiles of 16
        f32x4 qk[4];
        #pragma unroll
        for (int ct = 0; ct < 4; ++ct) {
            const float* krow = K + ((b * L_ + m0 + ct * 16 + lr) * D_ + lg * 8);
            f32x4 acc = {0.f, 0.f, 0.f, 0.f};
            acc = __builtin_amdgcn_mfma_f32_16x16x32_bf16(aq[0], pack8(krow),      acc, 0, 0, 0);
            acc = __builtin_amdgcn_mfma_f32_16x16x32_bf16(aq[1], pack8(krow + 32), acc, 0, 0, 0);
            qk[ct] = acc;
        }
        // positional scores: 5 shared 16-wide slices cover jj in [0, 80) for all 4 tiles
        const int jb = (L_ - 1) + m0 - t0 - 15;
        f32x4 pa[5];
        #pragma unroll
        for (int ss = 0; ss < 5; ++ss) {
            int j = jb + ss * 16 + lr;
            j = j < 0 ? 0 : (j > J_ - 1 ? J_ - 1 : j);   // clamp unused extremes
            const float* prow = P + ((b * J_ + j) * D_ + lg * 8);
            f32x4 acc = {0.f, 0.f, 0.f, 0.f};
            acc = __builtin_amdgcn_mfma_f32_16x16x32_bf16(aqp[0], pack8(prow),      acc, 0, 0, 0);
            acc = __builtin_amdgcn_mfma_f32_16x16x32_bf16(aqp[1], pack8(prow + 32), acc, 0, 0, 0);
            pa[ss] = acc;
        }
        // combine + mask + store + online stats
        #pragma unroll
        for (int r = 0; r < 4; ++r) {
            const int ti = lg * 4 + r;
            const int t  = t0 + ti;
            const int jj = 15 + lr - ti;                 // 0..30
            const int srcl = (lane & 48) | (jj & 15);
            float sv[4];
            #pragma unroll
            for (int ct = 0; ct < 4; ++ct) {
                float v0 = __shfl(pa[ct][r],     srcl);
                float v1 = __shfl(pa[ct + 1][r], srcl);
                float pos = (jj < 16) ? v0 : v1;
                float s = (qk[ct][r] + pos) * 0.125f;
                const int mcol = m0 + ct * 16 + lr;
                const int idx = (b * L_ + t) * L_ + mcol;
                int msk;
                if (flag == 0)      msk = m8[idx];
                else if (flag == 1) msk = m32[idx];
                else                msk = (mf[idx] != 0.f);
                if (msk) s = -__builtin_inff();
                sv[ct] = s;
                attn[idx] = s;
            }
            float cmax = fmaxf(fmaxf(sv[0], sv[1]), fmaxf(sv[2], sv[3]));
            cmax = fmaxf(cmax, __shfl_xor(cmax, 1));
            cmax = fmaxf(cmax, __shfl_xor(cmax, 2));
            cmax = fmaxf(cmax, __shfl_xor(cmax, 4));
            cmax = fmaxf(cmax, __shfl_xor(cmax, 8));
            float mn = fmaxf(m_run[r], cmax);
            float cs = __expf(sv[0] - mn) + __expf(sv[1] - mn)
                     + __expf(sv[2] - mn) + __expf(sv[3] - mn);
            cs += __shfl_xor(cs, 1);
            cs += __shfl_xor(cs, 2);
            cs += __shfl_xor(cs, 4);
            cs += __shfl_xor(cs, 8);
            l_run[r] = l_run[r] * __expf(m_run[r] - mn) + cs;
            m_run[r] = mn;
        }
    }
    if (lr == 0) {
        #pragma unroll
        for (int r = 0; r < 4; ++r) {
            const int t = t0 + lg * 4 + r;
            wmax[b * L_ + t] = m_run[r];
            wsum[b * L_ + t] = l_run[r];
        }
    }
}

// Kernel 2: probs = exp(logit - max) / sum (written in place over logits),
// O = probs @ V via MFMA with V staged transposed in LDS (stride 1048 bf16).
__global__ __launch_bounds__(256) void k2_pv(
    const float* __restrict__ V, float* __restrict__ attn,
    const float* __restrict__ wmax, const float* __restrict__ wsum,
    float* __restrict__ out)
{
    __shared__ unsigned short vt[64 * 1048];    // 134 KB, Vt[d][m]
    int bid = blockIdx.x;
    bid = (bid & 7) * 64 + (bid >> 3);
    const int b  = bid >> 4;
    const int rb = bid & 15;
    const int tid = threadIdx.x;

    // cooperative transpose V[1024][64] -> vt[64][1048] bf16
    {
        const int mbase = (tid >> 4) * 2;
        const int dbase = tid & 15;
        for (int it = 0; it < 32; ++it) {
            const int m = it * 32 + mbase;
            #pragma unroll
            for (int i = 0; i < 4; ++i) {
                const int d = dbase + 16 * i;
                float f0 = V[(b * L_ + m)     * D_ + d];
                float f1 = V[(b * L_ + m + 1) * D_ + d];
                unsigned u = (unsigned)f2bf(f0) | ((unsigned)f2bf(f1) << 16);
                *(unsigned*)&vt[d * 1048 + m] = u;
            }
        }
    }
    __syncthreads();

    const int lane = tid & 63;
    const int w    = tid >> 6;
    const int t0 = rb * 64 + w * 16;
    const int lr = lane & 15, lg = lane >> 4;
    const int t = t0 + lr;
    const float smax = wmax[b * L_ + t];
    const float inv  = 1.0f / wsum[b * L_ + t];
    float* arow = attn + ((b * L_ + t) * L_ + lg * 8);

    f32x4 acc[4] = {{0,0,0,0},{0,0,0,0},{0,0,0,0},{0,0,0,0}};
    for (int kc = 0; kc < 32; ++kc) {
        float4 x0 = *(float4*)(arow + kc * 32);
        float4 x1 = *(float4*)(arow + kc * 32 + 4);
        float p0 = __expf(x0.x - smax) * inv;
        float p1 = __expf(x0.y - smax) * inv;
        float p2 = __expf(x0.z - smax) * inv;
        float p3 = __expf(x0.w - smax) * inv;
        float p4 = __expf(x1.x - smax) * inv;
        float p5 = __expf(x1.y - smax) * inv;
        float p6 = __expf(x1.z - smax) * inv;
        float p7 = __expf(x1.w - smax) * inv;
        *(float4*)(arow + kc * 32)     = make_float4(p0, p1, p2, p3);
        *(float4*)(arow + kc * 32 + 4) = make_float4(p4, p5, p6, p7);
        bf16x8 ap;
        ap[0] = (short)f2bf(p0); ap[1] = (short)f2bf(p1);
        ap[2] = (short)f2bf(p2); ap[3] = (short)f2bf(p3);
        ap[4] = (short)f2bf(p4); ap[5] = (short)f2bf(p5);
        ap[6] = (short)f2bf(p6); ap[7] = (short)f2bf(p7);
        #pragma unroll
        for (int ct = 0; ct < 4; ++ct) {
            bf16x8 bv = *(const bf16x8*)&vt[(ct * 16 + lr) * 1048 + kc * 32 + lg * 8];
            acc[ct] = __builtin_amdgcn_mfma_f32_16x16x32_bf16(ap, bv, acc[ct], 0, 0, 0);
        }
    }
    #pragma unroll
    for (int ct = 0; ct < 4; ++ct) {
        #pragma unroll
        for (int r = 0; r < 4; ++r) {
            out[(b * L_ + t0 + lg * 4 + r) * D_ + ct * 16 + lr] = acc[ct][r];
        }
    }
}

extern "C" void kernel_launch(void* const* d_in, const int* in_sizes, int n_in,
                              void* d_out, int out_size, void* d_ws, size_t ws_size,
                              hipStream_t stream) {
    const float* q    = (const float*)d_in[0];
    const float* k    = (const float*)d_in[1];
    const float* v    = (const float*)d_in[2];
    const void*  mask = d_in[3];
    const float* P    = (const float*)d_in[4];
    const float* qp   = (const float*)d_in[5];

    float* out  = (float*)d_out;                  // [B, L, D]
    float* attn = out + B_ * L_ * D_;             // [B, L, L]

    float* wmax = (float*)d_ws;                   // [B*L]
    float* wsum = wmax + B_ * L_;                 // [B*L]
    int*   flag = (int*)(wsum + B_ * L_);

    detect_mask_kernel<<<1, 64, 0, stream>>>((const unsigned int*)mask, flag);
    k1_logits<<<B_ * (L_ / 64), 256, 0, stream>>>(q, k, qp, P, mask, flag, attn, wmax, wsum);
    k2_pv<<<B_ * (L_ / 64), 256, 0, stream>>>(v, attn, wmax, wsum, out);
}

// Round 3
// 185.758 us; speedup vs baseline: 1.7134x; 1.7134x over previous
//
#include <hip/hip_runtime.h>
#include <hip/hip_bf16.h>

typedef float f32x4 __attribute__((ext_vector_type(4)));
typedef short bf16x8 __attribute__((ext_vector_type(8)));
typedef unsigned uint4v __attribute__((ext_vector_type(4)));

#define B_ 32
#define L_ 1024
#define D_ 64
#define J_ 2047   // 2L-1
#define BL_ (B_ * L_)

// packed f32x2 -> bf16x2 (RNE), single instruction
__device__ __forceinline__ unsigned cvt_pk(float lo, float hi) {
    unsigned r;
    asm("v_cvt_pk_bf16_f32 %0, %1, %2" : "=v"(r) : "v"(lo), "v"(hi));
    return r;
}

__device__ __forceinline__ bf16x8 pack8n(const float* p) {
    float4 a = *(const float4*)p;
    float4 c = *(const float4*)(p + 4);
    union { bf16x8 s; uint4v u; } r;
    r.u[0] = cvt_pk(a.x, a.y);
    r.u[1] = cvt_pk(a.z, a.w);
    r.u[2] = cvt_pk(c.x, c.y);
    r.u[3] = cvt_pk(c.z, c.w);
    return r.s;
}

// Detect attn_mask storage: 0 = 1-byte bool, 1 = int32 0/1, 2 = float32 0.0/1.0
__global__ void detect_mask_kernel(const unsigned int* __restrict__ mw, int* __restrict__ flag) {
    if (threadIdx.x == 0) {
        int all01 = 1, allf = 1;
        for (int i = 0; i < 64; ++i) {
            unsigned w = mw[i];
            if (w > 1u) all01 = 0;
            if (w != 0u && w != 0x3F800000u) allf = 0;
        }
        *flag = all01 ? 1 : (allf ? 2 : 0);
    }
}

// Pack mask into bitmask: one u64 per 64 cols. grid*block = B*L*L/64 threads.
__global__ __launch_bounds__(256) void pack_mask(
    const void* __restrict__ mask, const int* __restrict__ flagp,
    unsigned long long* __restrict__ bm)
{
    const int flag = *flagp;
    const int g = blockIdx.x * 256 + threadIdx.x;
    unsigned long long bits = 0ull;
    if (flag == 0) {
        const uint4* p = (const uint4*)((const unsigned char*)mask + (size_t)g * 64);
        #pragma unroll
        for (int q = 0; q < 4; ++q) {
            uint4 v = p[q];
            unsigned w[4] = {v.x, v.y, v.z, v.w};
            #pragma unroll
            for (int a = 0; a < 4; ++a) {
                #pragma unroll
                for (int byt = 0; byt < 4; ++byt)
                    if ((w[a] >> (8 * byt)) & 0xFFu) bits |= 1ull << (q * 16 + a * 4 + byt);
            }
        }
    } else {  // int32 0/1 or float 0.0/1.0: nonzero word == masked
        const uint4* p = (const uint4*)((const unsigned*)mask + (size_t)g * 64);
        #pragma unroll
        for (int q = 0; q < 16; ++q) {
            uint4 v = p[q];
            if (v.x) bits |= 1ull << (q * 4 + 0);
            if (v.y) bits |= 1ull << (q * 4 + 1);
            if (v.z) bits |= 1ull << (q * 4 + 2);
            if (v.w) bits |= 1ull << (q * 4 + 3);
        }
    }
    bm[g] = bits;
}

// K1: logits = (Q K^T + stripe(Qp P^T))/8, mask -> -inf, write logits, partial
// row stats (max,sumexp) per column half. Block = 4 waves x 16 rows, 512 cols.
// K tile + P window staged in LDS (bf16, XOR-swizzled 16B slots), shared by waves.
template<int USE_BM>
__global__ __launch_bounds__(256, 4) void k1_logits(
    const float* __restrict__ Q, const float* __restrict__ K,
    const float* __restrict__ QP, const float* __restrict__ P,
    const void* __restrict__ mask, const int* __restrict__ flagp,
    const unsigned long long* __restrict__ bm,
    float* __restrict__ attn, float* __restrict__ wmax, float* __restrict__ wsum)
{
    __shared__ unsigned short kls[64 * 64];    // 8 KB : K rows [m0, m0+64) x 64d bf16
    __shared__ unsigned short pls[128 * 64];   // 16 KB: P rows [jbase, jbase+128) x 64d

    const int flag = USE_BM ? 0 : *flagp;
    int bid = blockIdx.x;
    bid = (bid & 7) * 128 + (bid >> 3);        // XCD swizzle (1024 = 8*128)
    const int b   = bid >> 5;
    const int rb  = (bid >> 1) & 15;
    const int cs  = bid & 1;                   // column half
    const int tid = threadIdx.x;
    const int lane = tid & 63;
    const int w    = tid >> 6;
    const int t0b  = rb * 64;
    const int t0   = t0b + w * 16;
    const int lr = lane & 15;
    const int lg = lane >> 4;
    const int offw = (3 - w) * 16;             // wave's offset into the P window

    bf16x8 aq[2], aqp[2];
    {
        const float* qrow  = Q  + (size_t)((b * L_ + t0 + lr) * D_ + lg * 8);
        const float* qprow = QP + (size_t)((b * L_ + t0 + lr) * D_ + lg * 8);
        aq[0]  = pack8n(qrow);   aq[1]  = pack8n(qrow + 32);
        aqp[0] = pack8n(qprow);  aqp[1] = pack8n(qprow + 32);
    }

    const unsigned char* m8 = (const unsigned char*)mask;
    const int*   m32 = (const int*)mask;
    const float* mf  = (const float*)mask;

    float m_run[4] = {-1e30f, -1e30f, -1e30f, -1e30f};
    float l_run[4] = {0.f, 0.f, 0.f, 0.f};

    for (int c = 0; c < 8; ++c) {
        const int m0 = cs * 512 + c * 64;
        if (c) __syncthreads();
        // --- stage K tile: 64 rows x 64 d, bf16, swizzled 16B slots ---
        {
            const int row = tid >> 2, cq = tid & 3;
            const float* src = K + (size_t)((b * L_ + m0 + row) * D_ + cq * 16);
            bf16x8 v0 = pack8n(src);
            bf16x8 v1 = pack8n(src + 8);
            const int s0 = cq * 2;
            *(bf16x8*)&kls[row * 64 + (((s0    ) ^ (row & 7)) << 3)] = v0;
            *(bf16x8*)&kls[row * 64 + (((s0 + 1) ^ (row & 7)) << 3)] = v1;
        }
        // --- stage P window: 128 rows x 64 d ---
        {
            const int pr = tid >> 1, ch = tid & 1;
            const int jbase = 1023 + m0 - t0b - 63;
            int j = jbase + pr;
            j = j < 0 ? 0 : (j > J_ - 1 ? J_ - 1 : j);
            const float* src = P + (size_t)((b * J_ + j) * D_ + ch * 32);
            #pragma unroll
            for (int s = 0; s < 4; ++s) {
                bf16x8 v = pack8n(src + s * 8);
                *(bf16x8*)&pls[pr * 64 + ((((ch << 2) + s) ^ (pr & 7)) << 3)] = v;
            }
        }
        __syncthreads();

        // --- content scores ---
        f32x4 qk[4];
        #pragma unroll
        for (int ct = 0; ct < 4; ++ct) {
            const int row = ct * 16 + lr;
            bf16x8 b0 = *(const bf16x8*)&kls[row * 64 + (((lg    ) ^ (row & 7)) << 3)];
            bf16x8 b1 = *(const bf16x8*)&kls[row * 64 + (((4 + lg) ^ (row & 7)) << 3)];
            f32x4 acc = {0.f, 0.f, 0.f, 0.f};
            acc = __builtin_amdgcn_mfma_f32_16x16x32_bf16(aq[0], b0, acc, 0, 0, 0);
            acc = __builtin_amdgcn_mfma_f32_16x16x32_bf16(aq[1], b1, acc, 0, 0, 0);
            qk[ct] = acc;
        }
        // --- positional scores: 5 shared slices ---
        f32x4 pa[5];
        #pragma unroll
        for (int ss = 0; ss < 5; ++ss) {
            const int prow = offw + ss * 16 + lr;
            bf16x8 b0 = *(const bf16x8*)&pls[prow * 64 + (((lg    ) ^ (prow & 7)) << 3)];
            bf16x8 b1 = *(const bf16x8*)&pls[prow * 64 + (((4 + lg) ^ (prow & 7)) << 3)];
            f32x4 acc = {0.f, 0.f, 0.f, 0.f};
            acc = __builtin_amdgcn_mfma_f32_16x16x32_bf16(aqp[0], b0, acc, 0, 0, 0);
            acc = __builtin_amdgcn_mfma_f32_16x16x32_bf16(aqp[1], b1, acc, 0, 0, 0);
            pa[ss] = acc;
        }
        // --- stripe combine + mask + store + lane-local online stats ---
        #pragma unroll
        for (int r = 0; r < 4; ++r) {
            const int ti = lg * 4 + r;
            const int t  = t0 + ti;
            const int jj = 15 + lr - ti;                 // 0..30
            const int srcl = (lane & 48) | (jj & 15);
            unsigned mlo = 0, mhi = 0;
            if (USE_BM) {
                unsigned long long mrow = bm[(b * L_ + t) * 16 + (m0 >> 6)] >> lr;
                mlo = (unsigned)mrow;
                mhi = (unsigned)(mrow >> 32);
            }
            float sv[4];
            #pragma unroll
            for (int ct = 0; ct < 4; ++ct) {
                float v0 = __shfl(pa[ct][r],     srcl);
                float v1 = __shfl(pa[ct + 1][r], srcl);
                float pos = (jj < 16) ? v0 : v1;
                float s = (qk[ct][r] + pos) * 0.125f;
                const int mcol = m0 + ct * 16 + lr;
                const size_t idx = (size_t)(b * L_ + t) * L_ + mcol;
                int msk;
                if (USE_BM) {
                    msk = (int)(((ct < 2) ? (mlo >> (ct * 16)) : (mhi >> ((ct - 2) * 16))) & 1u);
                } else {
                    if (flag == 0)      msk = m8[idx];
                    else if (flag == 1) msk = m32[idx];
                    else                msk = (mf[idx] != 0.f);
                }
                if (msk) s = -__builtin_inff();
                sv[ct] = s;
                attn[idx] = s;
            }
            float cm = fmaxf(fmaxf(sv[0], sv[1]), fmaxf(sv[2], sv[3]));
            float mn = fmaxf(m_run[r], cm);
            float e = __expf(sv[0] - mn) + __expf(sv[1] - mn)
                    + __expf(sv[2] - mn) + __expf(sv[3] - mn);
            l_run[r] = l_run[r] * __expf(m_run[r] - mn) + e;
            m_run[r] = mn;
        }
    }
    // final cross-lane merge within the 16-lane lr group
    #pragma unroll
    for (int r = 0; r < 4; ++r) {
        float m = m_run[r], l = l_run[r];
        #pragma unroll
        for (int d = 1; d < 16; d <<= 1) {
            float mo = __shfl_xor(m, d);
            float lo = __shfl_xor(l, d);
            float mn = fmaxf(m, mo);
            l = l * __expf(m - mn) + lo * __expf(mo - mn);
            m = mn;
        }
        if (lr == 0) {
            const int t = t0 + lg * 4 + r;
            wmax[cs * BL_ + b * L_ + t] = m;
            wsum[cs * BL_ + b * L_ + t] = l;
        }
    }
}

// K2: combine partial stats, probs = exp(logit-max)*inv written in place,
// O = probs @ V with V staged transposed in LDS.
__global__ __launch_bounds__(256) void k2_pv(
    const float* __restrict__ V, float* __restrict__ attn,
    const float* __restrict__ wmaxp, const float* __restrict__ wsump,
    float* __restrict__ out)
{
    __shared__ unsigned short vt[64 * 1048];    // 134 KB, Vt[d][m]
    int bid = blockIdx.x;
    bid = (bid & 7) * 64 + (bid >> 3);
    const int b  = bid >> 4;
    const int rb = bid & 15;
    const int tid = threadIdx.x;

    {
        const int mbase = (tid >> 4) * 2;
        const int dbase = tid & 15;
        for (int it = 0; it < 32; ++it) {
            const int m = it * 32 + mbase;
            #pragma unroll
            for (int i = 0; i < 4; ++i) {
                const int d = dbase + 16 * i;
                float f0 = V[(size_t)(b * L_ + m)     * D_ + d];
                float f1 = V[(size_t)(b * L_ + m + 1) * D_ + d];
                *(unsigned*)&vt[d * 1048 + m] = cvt_pk(f0, f1);
            }
        }
    }
    __syncthreads();

    const int lane = tid & 63;
    const int w    = tid >> 6;
    const int t0 = rb * 64 + w * 16;
    const int lr = lane & 15, lg = lane >> 4;
    const int t = t0 + lr;
    const int i = b * L_ + t;

    float m0p = wmaxp[i], m1p = wmaxp[BL_ + i];
    float l0  = wsump[i], l1  = wsump[BL_ + i];
    float smax = fmaxf(m0p, m1p);
    float inv  = 1.0f / (l0 * __expf(m0p - smax) + l1 * __expf(m1p - smax));

    float* arow = attn + ((size_t)i * L_ + lg * 8);

    f32x4 acc[4] = {{0,0,0,0},{0,0,0,0},{0,0,0,0},{0,0,0,0}};
    for (int kc = 0; kc < 32; ++kc) {
        float4 x0 = *(float4*)(arow + kc * 32);
        float4 x1 = *(float4*)(arow + kc * 32 + 4);
        float p0 = __expf(x0.x - smax) * inv;
        float p1 = __expf(x0.y - smax) * inv;
        float p2 = __expf(x0.z - smax) * inv;
        float p3 = __expf(x0.w - smax) * inv;
        float p4 = __expf(x1.x - smax) * inv;
        float p5 = __expf(x1.y - smax) * inv;
        float p6 = __expf(x1.z - smax) * inv;
        float p7 = __expf(x1.w - smax) * inv;
        *(float4*)(arow + kc * 32)     = make_float4(p0, p1, p2, p3);
        *(float4*)(arow + kc * 32 + 4) = make_float4(p4, p5, p6, p7);
        union { bf16x8 s; uint4v u; } ap;
        ap.u[0] = cvt_pk(p0, p1);
        ap.u[1] = cvt_pk(p2, p3);
        ap.u[2] = cvt_pk(p4, p5);
        ap.u[3] = cvt_pk(p6, p7);
        #pragma unroll
        for (int ct = 0; ct < 4; ++ct) {
            bf16x8 bv = *(const bf16x8*)&vt[(ct * 16 + lr) * 1048 + kc * 32 + lg * 8];
            acc[ct] = __builtin_amdgcn_mfma_f32_16x16x32_bf16(ap.s, bv, acc[ct], 0, 0, 0);
        }
    }
    #pragma unroll
    for (int ct = 0; ct < 4; ++ct) {
        #pragma unroll
        for (int r = 0; r < 4; ++r) {
            out[(size_t)(b * L_ + t0 + lg * 4 + r) * D_ + ct * 16 + lr] = acc[ct][r];
        }
    }
}

extern "C" void kernel_launch(void* const* d_in, const int* in_sizes, int n_in,
                              void* d_out, int out_size, void* d_ws, size_t ws_size,
                              hipStream_t stream) {
    const float* q    = (const float*)d_in[0];
    const float* k    = (const float*)d_in[1];
    const float* v    = (const float*)d_in[2];
    const void*  mask = d_in[3];
    const float* P    = (const float*)d_in[4];
    const float* qp   = (const float*)d_in[5];

    float* out  = (float*)d_out;                  // [B, L, D]
    float* attn = out + B_ * L_ * D_;             // [B, L, L]

    float* wmax = (float*)d_ws;                   // [2][B*L]
    float* wsum = wmax + 2 * BL_;                 // [2][B*L]
    int*   flag = (int*)(wsum + 2 * BL_);
    unsigned long long* bm =
        (unsigned long long*)((char*)d_ws + (size_t)(4 * BL_) * 4 + 64);
    const size_t need = (size_t)(4 * BL_) * 4 + 64 + (size_t)BL_ * 16 * 8;
    const int use_bm = (ws_size >= need);

    detect_mask_kernel<<<1, 64, 0, stream>>>((const unsigned int*)mask, flag);
    if (use_bm) {
        pack_mask<<<(BL_ * (L_ / 64)) / 256, 256, 0, stream>>>(mask, flag, bm);
        k1_logits<1><<<B_ * (L_ / 64) * 2, 256, 0, stream>>>(q, k, qp, P, mask, flag, bm, attn, wmax, wsum);
    } else {
        k1_logits<0><<<B_ * (L_ / 64) * 2, 256, 0, stream>>>(q, k, qp, P, mask, flag, bm, attn, wmax, wsum);
    }
    k2_pv<<<B_ * (L_ / 64), 256, 0, stream>>>(v, attn, wmax, wsum, out);
}